// Round 10
// baseline (250.963 us; speedup 1.0000x reference)
//
#include <hip/hip_runtime.h>
#include <hip/hip_bf16.h>

#define B_  4
#define S_  2048
#define H_  1024
#define NH_ 16
#define HD_ 64

typedef __bf16 bf16;
typedef __attribute__((ext_vector_type(8))) __bf16 bf16x8;
typedef __attribute__((ext_vector_type(4))) __bf16 bf16x4;
typedef __attribute__((ext_vector_type(2))) __bf16 bf16x2;
typedef __attribute__((ext_vector_type(4))) float f32x4;

typedef const __attribute__((address_space(1))) char* gptr_t;
typedef __attribute__((address_space(3))) char* lptr_t;
#define GLOAD_LDS16(g, l) __builtin_amdgcn_global_load_lds((gptr_t)(g), (lptr_t)(l), 16, 0, 0)

__device__ __forceinline__ f32x4 mfma16(bf16x8 a, bf16x8 b, f32x4 c) {
    return __builtin_amdgcn_mfma_f32_16x16x32_bf16(a, b, c, 0, 0, 0);
}

// XCD-aware block swizzle (T1, m204 bijective; all grids here have nwg%8==0):
// dispatch id i -> work id w so each XCD gets a CONTIGUOUS chunk of work ids.
__device__ __forceinline__ void swz_bid(int& bx, int& by) {
    const int gx = gridDim.x;
    const int nwg = gx * gridDim.y;
    const int i = blockIdx.x + gx * blockIdx.y;
    const int w = (i & 7) * (nwg >> 3) + (i >> 3);
    bx = w % gx;
    by = w / gx;
}

// ---------------- fused prep: x->bf16, weights->bf16, RoPE cs table ----------------
// blocks [0,8192): x (2097152 float4s); [8192,12288): weights (1048576 float4s);
// [12288,12544): cs table (65536 entries of (cos,sin)).
__global__ void k_prep(const float* __restrict__ x,
                       const float* __restrict__ Wq, const float* __restrict__ Wk,
                       const float* __restrict__ Wv, const float* __restrict__ Wo,
                       bf16* __restrict__ xb, bf16* __restrict__ wqkv,
                       bf16* __restrict__ wob, float2* __restrict__ csT) {
    const int blk = blockIdx.x, tid = threadIdx.x;
    if (blk < 8192) {
        int i = blk * 256 + tid;
        float4 v = ((const float4*)x)[i];
        bf16x4 o;
        o[0] = (__bf16)v.x; o[1] = (__bf16)v.y; o[2] = (__bf16)v.z; o[3] = (__bf16)v.w;
        *(bf16x4*)(xb + i * 4) = o;
    } else if (blk < 12288) {
        int i = (blk - 8192) * 256 + tid;        // 0..1048575 (float4 units)
        int region = i >> 18;                    // 262144 float4s per weight
        int j = i & 262143;
        const float* src = region == 0 ? Wq : region == 1 ? Wk : region == 2 ? Wv : Wo;
        bf16* dst = region < 3 ? wqkv + (size_t)region * 1048576 : wob;
        float4 v = ((const float4*)src)[j];
        bf16x4 o;
        o[0] = (__bf16)v.x; o[1] = (__bf16)v.y; o[2] = (__bf16)v.z; o[3] = (__bf16)v.w;
        *(bf16x4*)(dst + j * 4) = o;
    } else {
        int i = (blk - 12288) * 256 + tid;       // 0..65535
        int s = i >> 5, d = i & 31;
        float inv = powf(10000.0f, -(float)d * (1.0f / 32.0f));
        float ang = (float)s * inv;
        csT[i] = make_float2(cosf(ang), sinf(ang));
    }
}

// ---------------- GEMM: out[m][n] = sum_k A[m][k] * W[n][k] ----------------
// 128x128 tile, 4 waves (2x2 of 64x64), BK=64 single-buffered
// (proven sync;STAGE;sync;COMP discipline), XOR-swizzled LDS, 16x16x32 MFMA.
// EPI 0: n in [0,3072) -> q/k (B,NH,S,HD) bf16 with RoPE, stored D-INTERLEAVED
//        (pair (d,d+32) at positions 2d,2d+1; same permutation for q and k ->
//        QK^T invariant; q pre-scaled 0.125*log2e for exp2-domain softmax);
//        v -> (B,NH,HD,S) transposed with kv-permuted 64-tiles (b128 PV reads).
// EPI 1: fp32 row-major out (N=1024).
template<int EPI>
__global__ __launch_bounds__(256) void k_gemm(
        const bf16* __restrict__ A, const bf16* __restrict__ Bw,
        bf16* __restrict__ q_out, bf16* __restrict__ k_out, bf16* __restrict__ v_out,
        const float2* __restrict__ csT, float* __restrict__ fout) {
    __shared__ bf16 As[128 * 64];
    __shared__ bf16 Bs[128 * 64];
    const int t = threadIdx.x, l = t & 63, w = t >> 6;
    const int lr = l & 15, hi = l >> 4;
    const int sw = (lr & 7) << 4;                  // read-side XOR swizzle
    int bx, by;
    swz_bid(bx, by);
    const int m0 = by * 128, n0 = bx * 128;
    const int wr = (w >> 1) * 64, wc = (w & 1) * 64;
    f32x4 acc[4][4] = {};

    for (int k0 = 0; k0 < 1024; k0 += 64) {
        __syncthreads();                           // LDS readers of prev slice done
#pragma unroll
        for (int i = 0; i < 4; ++i) {
            int o = i * 4096 + t * 16;             // byte offset in 16KB tile
            int row = o >> 7, colb = o & 127;      // 128B rows (64 bf16)
            int scol = colb ^ ((row & 7) << 4);    // pre-swizzled source
            GLOAD_LDS16((const char*)A + ((size_t)(m0 + row) * 1024 + k0) * 2 + scol,
                        (char*)As + o);
            GLOAD_LDS16((const char*)Bw + ((size_t)(n0 + row) * 1024 + k0) * 2 + scol,
                        (char*)Bs + o);
        }
        __syncthreads();                           // implicit vmcnt(0): slice ready
#pragma unroll
        for (int kk = 0; kk < 2; ++kk) {
            bf16x8 af[4], bfr[4];
#pragma unroll
            for (int mi = 0; mi < 4; ++mi)
                af[mi] = *(const bf16x8*)((const char*)As
                          + (wr + mi * 16 + lr) * 128 + ((kk * 64 + hi * 16) ^ sw));
#pragma unroll
            for (int ni = 0; ni < 4; ++ni)
                bfr[ni] = *(const bf16x8*)((const char*)Bs
                          + (wc + ni * 16 + lr) * 128 + ((kk * 64 + hi * 16) ^ sw));
#pragma unroll
            for (int mi = 0; mi < 4; ++mi)
#pragma unroll
                for (int ni = 0; ni < 4; ++ni)
                    acc[mi][ni] = mfma16(af[mi], bfr[ni], acc[mi][ni]);
        }
    }

    // D layout (m89-verified): col = lr, row = hi*4 + reg
    if (EPI == 0) {
        const int nbase = n0 + wc;               // 64-aligned -> one head
        const int which = nbase >> 10;           // 0:q 1:k 2:v
        const int head = (nbase & 1023) >> 6;
        if (which == 2) {
            // V^T: vt[bh][d][perm(s)]; within each 64-wide s-tile:
            // s bits (ks,u,h2,r) = (b5, b4, b3:2, b1:0) -> pos = ks*32 + h2*8 + u*4 + r
#pragma unroll
            for (int mi = 0; mi < 4; ++mi) {
                int m = m0 + wr + mi * 16 + hi * 4;      // s base (r=0)
                int bb = m >> 11, s = m & 2047;
                int st = s & 63;
                int pos = ((st >> 5) & 1) * 32 + ((st >> 2) & 3) * 8 + ((st >> 4) & 1) * 4;
                int sp = (s & ~63) | pos;
                size_t vbase = (size_t)(bb * NH_ + head) * HD_;
#pragma unroll
                for (int ni = 0; ni < 4; ++ni) {
                    bf16x4 o;
#pragma unroll
                    for (int r = 0; r < 4; ++r) o[r] = (__bf16)acc[mi][ni][r];
                    *(bf16x4*)(v_out + (vbase + ni * 16 + lr) * (size_t)S_ + sp) = o;
                }
            }
        } else {
            bf16* dst = which == 0 ? q_out : k_out;
            // fold 1/sqrt(HD) * log2(e) into Q -> scores land in exp2 domain
            const float qsc = which == 0 ? 0.125f * 1.4426950408889634f : 1.0f;
#pragma unroll
            for (int mi = 0; mi < 4; ++mi) {
#pragma unroll
                for (int r = 0; r < 4; ++r) {
                    int m = m0 + wr + mi * 16 + hi * 4 + r;
                    int bb = m >> 11, s = m & 2047;
                    size_t base = (((size_t)bb * NH_ + head) * S_ + s) * HD_;
#pragma unroll
                    for (int ni = 0; ni < 2; ++ni) {
                        int d = ni * 16 + lr;            // 0..31
                        float2 cs = csT[s * 32 + d];
                        float c = cs.x * qsc, sn = cs.y * qsc;
                        float x1 = acc[mi][ni][r], x2 = acc[mi][ni + 2][r];
                        bf16x2 o;
                        o[0] = (__bf16)(x1 * c - x2 * sn);   // rotated d
                        o[1] = (__bf16)(x2 * c + x1 * sn);   // rotated d+32
                        *(bf16x2*)(dst + base + 2 * d) = o;  // interleaved pair
                    }
                }
            }
        }
    } else {
#pragma unroll
        for (int mi = 0; mi < 4; ++mi)
#pragma unroll
            for (int ni = 0; ni < 4; ++ni)
#pragma unroll
                for (int r = 0; r < 4; ++r)
                    fout[(size_t)(m0 + wr + mi * 16 + hi * 4 + r) * 1024
                         + (n0 + wc + ni * 16 + lr)] = acc[mi][ni][r];
    }
}

// ---------------- Flash attention: LDS-staged KV, double-buffered ----------------
// 8 waves x 32 q-rows = 256 q per block (512 thr); KV tiles of 64 in LDS
// (K row-major [kv][d-interleaved], V^T [d][perm(kv)], XOR-swizzled col^=(row&7)<<4).
// Q/K rows use the d-interleaved RoPE layout -> QK^T dot invariant.
// S^T = mfma(K, Q): lane owns q-col lr; scores at kv = g*16 + hi*4 + r.
// NO max subtraction: p = exp2(s) directly (fp32 range >> score range; masked
// s = -inf -> exp2 = 0 exact). Denominator via mfma(ones, P); final O = acc/L.
__global__ __launch_bounds__(512, 4) void k_attn(
        const bf16* __restrict__ qr, const bf16* __restrict__ kr,
        const bf16* __restrict__ vt, const int* __restrict__ mask,
        bf16* __restrict__ aout) {
    __shared__ bf16 Ks[2][64 * 64];
    __shared__ bf16 Vs[2][64 * 64];
    const int t = threadIdx.x, l = t & 63, w = t >> 6;
    const int lr = l & 15, hi = l >> 4;
    const int sw = (lr & 7) << 4;                  // read-side XOR swizzle
    int bx, by;
    swz_bid(bx, by);                               // same-bh blocks -> same XCD L2
    const int bh = by, b = bh >> 4, head = bh & 15;
    const int qbase = bx * 256 + w * 32;

    const bf16* Qb = qr + (size_t)bh * S_ * HD_;
    const char* Kg = (const char*)(kr + (size_t)bh * S_ * HD_);
    const char* Vg = (const char*)(vt + (size_t)bh * HD_ * S_);   // [d][perm(s)]
    const int* mrow = mask + b * S_;

    bf16x8 qf[2][2];
#pragma unroll
    for (int qh = 0; qh < 2; ++qh)
#pragma unroll
        for (int h = 0; h < 2; ++h)
            qf[qh][h] = *(const bf16x8*)(Qb + (size_t)(qbase + qh * 16 + lr) * HD_ + h * 32 + hi * 8);

    bf16x8 onesf;
#pragma unroll
    for (int j = 0; j < 8; ++j) onesf[j] = (__bf16)1.0f;

    int anyz0 = 0;
    for (int i = l; i < S_ / 4; i += 64) {
        int4 m4 = ((const int4*)mrow)[i];
        anyz0 |= (m4.x == 0) | (m4.y == 0) | (m4.z == 0) | (m4.w == 0);
    }
    const bool anyz = __any(anyz0);

    f32x4 acc[4][2] = {};
    f32x4 accL[2] = {};                  // softmax denominator (all regs equal)

    // stage tile kv0 into buffer buf: K 8KB + V 8KB, pre-swizzled source (512 thr)
    auto STAGE = [&](int buf, int kv0) {
        int o = t * 16;                            // 0..8191
        int row = o >> 7, colb = o & 127;          // 128B rows (64 bf16)
        int scol = colb ^ ((row & 7) << 4);
        GLOAD_LDS16(Kg + (size_t)(kv0 + row) * 128 + scol, (char*)Ks[buf] + o);
        GLOAD_LDS16(Vg + (size_t)row * (S_ * 2) + (size_t)kv0 * 2 + scol,
                    (char*)Vs[buf] + o);
    };

    // one kv-tile of 64 from LDS buffer buf (compile-time), kv origin kv0
    auto TILE = [&](int buf, int kv0) {
        const char* Kc = (const char*)Ks[buf];
        const char* Vc = (const char*)Vs[buf];

        // ---- QK^T ----
        f32x4 st[4][2] = {};
#pragma unroll
        for (int g = 0; g < 4; ++g) {
            int rb = (g * 16 + lr) * 128;
            bf16x8 kf0 = *(const bf16x8*)(Kc + rb + ((hi * 16) ^ sw));
            bf16x8 kf1 = *(const bf16x8*)(Kc + rb + ((64 + hi * 16) ^ sw));
            st[g][0] = mfma16(kf0, qf[0][0], st[g][0]);
            st[g][0] = mfma16(kf1, qf[0][1], st[g][0]);
            st[g][1] = mfma16(kf0, qf[1][0], st[g][1]);
            st[g][1] = mfma16(kf1, qf[1][1], st[g][1]);
        }

        if (anyz) {
#pragma unroll
            for (int g = 0; g < 4; ++g) {
                int4 mv = *(const int4*)(mrow + kv0 + g * 16 + hi * 4);
#pragma unroll
                for (int qh = 0; qh < 2; ++qh) {
                    st[g][qh][0] = mv.x ? st[g][qh][0] : -INFINITY;
                    st[g][qh][1] = mv.y ? st[g][qh][1] : -INFINITY;
                    st[g][qh][2] = mv.z ? st[g][qh][2] : -INFINITY;
                    st[g][qh][3] = mv.w ? st[g][qh][3] : -INFINITY;
                }
            }
        }

        // ---- p = exp2(s), straight to bf16 ----
        bf16x8 pB[2][2];                 // [qh][ks]
#pragma unroll
        for (int qh = 0; qh < 2; ++qh)
#pragma unroll
            for (int g = 0; g < 4; ++g)
#pragma unroll
                for (int r = 0; r < 4; ++r)
                    pB[qh][g >> 1][(g & 1) * 4 + r] =
                        (__bf16)__builtin_exp2f(st[g][qh][r]);

        // ---- PV + denominator (mfma with ones-row), T5 priority hint ----
        __builtin_amdgcn_s_setprio(1);
        accL[0] = mfma16(onesf, pB[0][0], accL[0]);
        accL[0] = mfma16(onesf, pB[0][1], accL[0]);
        accL[1] = mfma16(onesf, pB[1][0], accL[1]);
        accL[1] = mfma16(onesf, pB[1][1], accL[1]);
#pragma unroll
        for (int dt = 0; dt < 4; ++dt) {
            const char* vrow = Vc + (dt * 16 + lr) * 128;
#pragma unroll
            for (int ks = 0; ks < 2; ++ks) {
                bf16x8 vf = *(const bf16x8*)(vrow + ((ks * 64 + hi * 16) ^ sw));
                acc[dt][0] = mfma16(vf, pB[0][ks], acc[dt][0]);
                acc[dt][1] = mfma16(vf, pB[1][ks], acc[dt][1]);
            }
        }
        __builtin_amdgcn_s_setprio(0);
    };

    STAGE(0, 0);
    const int NT = S_ / 64;              // 32, even
    for (int ti = 0; ti < NT; ti += 2) {
        __syncthreads();
        if (ti + 1 < NT) STAGE(1, (ti + 1) * 64);
        TILE(0, ti * 64);
        __syncthreads();
        if (ti + 2 < NT) STAGE(0, (ti + 2) * 64);
        TILE(1, (ti + 1) * 64);
    }

    float inv[2] = {1.0f / accL[0][0], 1.0f / accL[1][0]};
#pragma unroll
    for (int qh = 0; qh < 2; ++qh) {
        size_t obase = ((size_t)(b * S_ + qbase + qh * 16 + lr)) * H_ + head * HD_;
#pragma unroll
        for (int dt = 0; dt < 4; ++dt) {
            bf16x4 o;
#pragma unroll
            for (int r = 0; r < 4; ++r) o[r] = (__bf16)(acc[dt][qh][r] * inv[qh]);
            *(bf16x4*)(aout + obase + dt * 16 + hi * 4) = o;
        }
    }
}

extern "C" void kernel_launch(void* const* d_in, const int* in_sizes, int n_in,
                              void* d_out, int out_size, void* d_ws, size_t ws_size,
                              hipStream_t stream) {
    const float* x  = (const float*)d_in[0];
    const int* mask = (const int*)d_in[1];
    const float* Wq = (const float*)d_in[2];
    const float* Wk = (const float*)d_in[3];
    const float* Wv = (const float*)d_in[4];
    const float* Wo = (const float*)d_in[5];
    float* out = (float*)d_out;

    char* ws = (char*)d_ws;
    bf16* xb    = (bf16*)ws;                               // 16 MB (reused as attn out)
    bf16* wqkv  = (bf16*)(ws + (size_t)16 * 1048576);      // 6 MB
    bf16* wob   = (bf16*)(ws + (size_t)22 * 1048576);      // 2 MB
    bf16* qr    = (bf16*)(ws + (size_t)24 * 1048576);      // 16 MB (d-interleaved RoPE)
    bf16* kr    = (bf16*)(ws + (size_t)40 * 1048576);      // 16 MB (d-interleaved RoPE)
    bf16* vtw   = (bf16*)(ws + (size_t)56 * 1048576);      // 16 MB (V^T: [bh][d][perm(s)])
    float2* csT = (float2*)(ws + (size_t)72 * 1048576);    // 512 KB (cos,sin)

    // fused prep: x->bf16, weights->bf16, RoPE table (one launch)
    k_prep<<<12544, 256, 0, stream>>>(x, Wq, Wk, Wv, Wo, xb, wqkv, wob, csT);

    // QKV projection + RoPE + relayout (V transposed+permuted, Q exp2-scaled)
    k_gemm<0><<<dim3(24, 64), 256, 0, stream>>>(xb, wqkv, qr, kr, vtw, csT, nullptr);

    // flash attention -> (B,S,H) bf16 (reuse xb region)
    k_attn<<<dim3(8, 64), 512, 0, stream>>>(qr, kr, vtw, mask, xb);

    // output projection -> fp32
    k_gemm<1><<<dim3(8, 64), 256, 0, stream>>>(xb, wob, nullptr, nullptr, nullptr,
                                               nullptr, out);
}

// Round 12
// 203.239 us; speedup vs baseline: 1.2348x; 1.2348x over previous
//
#include <hip/hip_runtime.h>
#include <hip/hip_bf16.h>

#define B_  4
#define S_  2048
#define H_  1024
#define NH_ 16
#define HD_ 64

typedef __bf16 bf16;
typedef __attribute__((ext_vector_type(8))) __bf16 bf16x8;
typedef __attribute__((ext_vector_type(4))) __bf16 bf16x4;
typedef __attribute__((ext_vector_type(4))) float f32x4;

typedef const __attribute__((address_space(1))) char* gptr_t;
typedef __attribute__((address_space(3))) char* lptr_t;
#define GLOAD_LDS16(g, l) __builtin_amdgcn_global_load_lds((gptr_t)(g), (lptr_t)(l), 16, 0, 0)

__device__ __forceinline__ f32x4 mfma16(bf16x8 a, bf16x8 b, f32x4 c) {
    return __builtin_amdgcn_mfma_f32_16x16x32_bf16(a, b, c, 0, 0, 0);
}

// XCD-aware block swizzle (T1, m204 bijective; all grids here have nwg%8==0):
// dispatch id i -> work id w so each XCD gets a CONTIGUOUS chunk of work ids.
__device__ __forceinline__ void swz_bid(int& bx, int& by) {
    const int gx = gridDim.x;
    const int nwg = gx * gridDim.y;
    const int i = blockIdx.x + gx * blockIdx.y;
    const int w = (i & 7) * (nwg >> 3) + (i >> 3);
    bx = w % gx;
    by = w / gx;
}

// ---------------- fused prep: x->bf16, weights->bf16, RoPE tables ----------------
// blocks [0,8192): x (2097152 float4s); [8192,12288): weights (1048576 float4s);
// [12288,12544): cos/sin tables (65536 entries each, separate arrays).
__global__ void k_prep(const float* __restrict__ x,
                       const float* __restrict__ Wq, const float* __restrict__ Wk,
                       const float* __restrict__ Wv, const float* __restrict__ Wo,
                       bf16* __restrict__ xb, bf16* __restrict__ wqkv,
                       bf16* __restrict__ wob,
                       float* __restrict__ cosT, float* __restrict__ sinT) {
    const int blk = blockIdx.x, tid = threadIdx.x;
    if (blk < 8192) {
        int i = blk * 256 + tid;
        float4 v = ((const float4*)x)[i];
        bf16x4 o;
        o[0] = (__bf16)v.x; o[1] = (__bf16)v.y; o[2] = (__bf16)v.z; o[3] = (__bf16)v.w;
        *(bf16x4*)(xb + i * 4) = o;
    } else if (blk < 12288) {
        int i = (blk - 8192) * 256 + tid;        // 0..1048575 (float4 units)
        int region = i >> 18;                    // 262144 float4s per weight
        int j = i & 262143;
        const float* src = region == 0 ? Wq : region == 1 ? Wk : region == 2 ? Wv : Wo;
        bf16* dst = region < 3 ? wqkv + (size_t)region * 1048576 : wob;
        float4 v = ((const float4*)src)[j];
        bf16x4 o;
        o[0] = (__bf16)v.x; o[1] = (__bf16)v.y; o[2] = (__bf16)v.z; o[3] = (__bf16)v.w;
        *(bf16x4*)(dst + j * 4) = o;
    } else {
        int i = (blk - 12288) * 256 + tid;       // 0..65535
        int s = i >> 5, d = i & 31;
        float inv = powf(10000.0f, -(float)d * (1.0f / 32.0f));
        float ang = (float)s * inv;
        cosT[i] = cosf(ang);
        sinT[i] = sinf(ang);
    }
}

// ---------------- GEMM: out[m][n] = sum_k A[m][k] * W[n][k] ----------------
// 128x128 tile, 4 waves (2x2 of 64x64), BK=64 single-buffered
// (proven sync;STAGE;sync;COMP discipline), XOR-swizzled LDS, 16x16x32 MFMA.
// EXACT r9 structure (207 us, passed) — no launch_bounds cap, scalar RoPE stores.
// EPI 0: n in [0,3072) -> q/k (B,NH,S,HD) bf16 with RoPE
//        (q pre-scaled 0.125*log2e for exp2-domain softmax);
//        v -> (B,NH,HD,S) transposed with kv-permuted 64-tiles (b128 PV reads).
// EPI 1: fp32 row-major out (N=1024).
template<int EPI>
__global__ __launch_bounds__(256) void k_gemm(
        const bf16* __restrict__ A, const bf16* __restrict__ Bw,
        bf16* __restrict__ q_out, bf16* __restrict__ k_out, bf16* __restrict__ v_out,
        const float* __restrict__ cosT, const float* __restrict__ sinT,
        float* __restrict__ fout) {
    __shared__ bf16 As[128 * 64];
    __shared__ bf16 Bs[128 * 64];
    const int t = threadIdx.x, l = t & 63, w = t >> 6;
    const int lr = l & 15, hi = l >> 4;
    const int sw = (lr & 7) << 4;                  // read-side XOR swizzle
    int bx, by;
    swz_bid(bx, by);
    const int m0 = by * 128, n0 = bx * 128;
    const int wr = (w >> 1) * 64, wc = (w & 1) * 64;
    f32x4 acc[4][4] = {};

    for (int k0 = 0; k0 < 1024; k0 += 64) {
        __syncthreads();                           // LDS readers of prev slice done
#pragma unroll
        for (int i = 0; i < 4; ++i) {
            int o = i * 4096 + t * 16;             // byte offset in 16KB tile
            int row = o >> 7, colb = o & 127;      // 128B rows (64 bf16)
            int scol = colb ^ ((row & 7) << 4);    // pre-swizzled source
            GLOAD_LDS16((const char*)A + ((size_t)(m0 + row) * 1024 + k0) * 2 + scol,
                        (char*)As + o);
            GLOAD_LDS16((const char*)Bw + ((size_t)(n0 + row) * 1024 + k0) * 2 + scol,
                        (char*)Bs + o);
        }
        __syncthreads();                           // implicit vmcnt(0): slice ready
#pragma unroll
        for (int kk = 0; kk < 2; ++kk) {
            bf16x8 af[4], bfr[4];
#pragma unroll
            for (int mi = 0; mi < 4; ++mi)
                af[mi] = *(const bf16x8*)((const char*)As
                          + (wr + mi * 16 + lr) * 128 + ((kk * 64 + hi * 16) ^ sw));
#pragma unroll
            for (int ni = 0; ni < 4; ++ni)
                bfr[ni] = *(const bf16x8*)((const char*)Bs
                          + (wc + ni * 16 + lr) * 128 + ((kk * 64 + hi * 16) ^ sw));
#pragma unroll
            for (int mi = 0; mi < 4; ++mi)
#pragma unroll
                for (int ni = 0; ni < 4; ++ni)
                    acc[mi][ni] = mfma16(af[mi], bfr[ni], acc[mi][ni]);
        }
    }

    // D layout (m89-verified): col = lr, row = hi*4 + reg
    if (EPI == 0) {
        const int nbase = n0 + wc;               // 64-aligned -> one head
        const int which = nbase >> 10;           // 0:q 1:k 2:v
        const int head = (nbase & 1023) >> 6;
        if (which == 2) {
            // V^T: vt[bh][d][perm(s)]; within each 64-wide s-tile:
            // s bits (ks,u,h2,r) = (b5, b4, b3:2, b1:0) -> pos = ks*32 + h2*8 + u*4 + r
#pragma unroll
            for (int mi = 0; mi < 4; ++mi) {
                int m = m0 + wr + mi * 16 + hi * 4;      // s base (r=0)
                int bb = m >> 11, s = m & 2047;
                int st = s & 63;
                int pos = ((st >> 5) & 1) * 32 + ((st >> 2) & 3) * 8 + ((st >> 4) & 1) * 4;
                int sp = (s & ~63) | pos;
                size_t vbase = (size_t)(bb * NH_ + head) * HD_;
#pragma unroll
                for (int ni = 0; ni < 4; ++ni) {
                    bf16x4 o;
#pragma unroll
                    for (int r = 0; r < 4; ++r) o[r] = (__bf16)acc[mi][ni][r];
                    *(bf16x4*)(v_out + (vbase + ni * 16 + lr) * (size_t)S_ + sp) = o;
                }
            }
        } else {
            bf16* dst = which == 0 ? q_out : k_out;
            // fold 1/sqrt(HD) * log2(e) into Q -> scores land in exp2 domain
            const float qsc = which == 0 ? 0.125f * 1.4426950408889634f : 1.0f;
#pragma unroll
            for (int mi = 0; mi < 4; ++mi) {
#pragma unroll
                for (int r = 0; r < 4; ++r) {
                    int m = m0 + wr + mi * 16 + hi * 4 + r;
                    int bb = m >> 11, s = m & 2047;
                    size_t base = (((size_t)bb * NH_ + head) * S_ + s) * HD_;
#pragma unroll
                    for (int ni = 0; ni < 2; ++ni) {
                        int d = ni * 16 + lr;            // 0..31
                        float c = cosT[s * 32 + d] * qsc, sn = sinT[s * 32 + d] * qsc;
                        float x1 = acc[mi][ni][r], x2 = acc[mi][ni + 2][r];
                        dst[base + d]      = (__bf16)(x1 * c - x2 * sn);
                        dst[base + d + 32] = (__bf16)(x2 * c + x1 * sn);
                    }
                }
            }
        }
    } else {
#pragma unroll
        for (int mi = 0; mi < 4; ++mi)
#pragma unroll
            for (int ni = 0; ni < 4; ++ni)
#pragma unroll
                for (int r = 0; r < 4; ++r)
                    fout[(size_t)(m0 + wr + mi * 16 + hi * 4 + r) * 1024
                         + (n0 + wc + ni * 16 + lr)] = acc[mi][ni][r];
    }
}

// ---------------- Flash attention: LDS-staged KV, double-buffered ----------------
// 8 waves x 32 q-rows = 256 q per block (512 thr); KV tiles of 64 in LDS
// (K row-major [kv][d], V^T [d][perm(kv)], both XOR-swizzled col^=(row&7)<<4).
// S^T = mfma(K, Q): lane owns q-col lr; scores at kv = g*16 + hi*4 + r.
// NO max subtraction: p = exp2(s) directly (fp32 range >> score range; masked
// s = -inf -> exp2 = 0 exact). Denominator via mfma(ones, P); final O = acc/L.
__global__ __launch_bounds__(512, 4) void k_attn(
        const bf16* __restrict__ qr, const bf16* __restrict__ kr,
        const bf16* __restrict__ vt, const int* __restrict__ mask,
        bf16* __restrict__ aout) {
    __shared__ bf16 Ks[2][64 * 64];
    __shared__ bf16 Vs[2][64 * 64];
    const int t = threadIdx.x, l = t & 63, w = t >> 6;
    const int lr = l & 15, hi = l >> 4;
    const int sw = (lr & 7) << 4;                  // read-side XOR swizzle
    int bx, by;
    swz_bid(bx, by);                               // same-bh blocks -> same XCD L2
    const int bh = by, b = bh >> 4, head = bh & 15;
    const int qbase = bx * 256 + w * 32;

    const bf16* Qb = qr + (size_t)bh * S_ * HD_;
    const char* Kg = (const char*)(kr + (size_t)bh * S_ * HD_);
    const char* Vg = (const char*)(vt + (size_t)bh * HD_ * S_);   // [d][perm(s)]
    const int* mrow = mask + b * S_;

    bf16x8 qf[2][2];
#pragma unroll
    for (int qh = 0; qh < 2; ++qh)
#pragma unroll
        for (int h = 0; h < 2; ++h)
            qf[qh][h] = *(const bf16x8*)(Qb + (size_t)(qbase + qh * 16 + lr) * HD_ + h * 32 + hi * 8);

    bf16x8 onesf;
#pragma unroll
    for (int j = 0; j < 8; ++j) onesf[j] = (__bf16)1.0f;

    int anyz0 = 0;
    for (int i = l; i < S_ / 4; i += 64) {
        int4 m4 = ((const int4*)mrow)[i];
        anyz0 |= (m4.x == 0) | (m4.y == 0) | (m4.z == 0) | (m4.w == 0);
    }
    const bool anyz = __any(anyz0);

    f32x4 acc[4][2] = {};
    f32x4 accL[2] = {};                  // softmax denominator (all regs equal)

    // stage tile kv0 into buffer buf: K 8KB + V 8KB, pre-swizzled source (512 thr)
    auto STAGE = [&](int buf, int kv0) {
        int o = t * 16;                            // 0..8191
        int row = o >> 7, colb = o & 127;          // 128B rows (64 bf16)
        int scol = colb ^ ((row & 7) << 4);
        GLOAD_LDS16(Kg + (size_t)(kv0 + row) * 128 + scol, (char*)Ks[buf] + o);
        GLOAD_LDS16(Vg + (size_t)row * (S_ * 2) + (size_t)kv0 * 2 + scol,
                    (char*)Vs[buf] + o);
    };

    // one kv-tile of 64 from LDS buffer buf (compile-time), kv origin kv0
    auto TILE = [&](int buf, int kv0) {
        const char* Kc = (const char*)Ks[buf];
        const char* Vc = (const char*)Vs[buf];

        // ---- QK^T ----
        f32x4 st[4][2] = {};
#pragma unroll
        for (int g = 0; g < 4; ++g) {
            int rb = (g * 16 + lr) * 128;
            bf16x8 kf0 = *(const bf16x8*)(Kc + rb + ((hi * 16) ^ sw));
            bf16x8 kf1 = *(const bf16x8*)(Kc + rb + ((64 + hi * 16) ^ sw));
            st[g][0] = mfma16(kf0, qf[0][0], st[g][0]);
            st[g][0] = mfma16(kf1, qf[0][1], st[g][0]);
            st[g][1] = mfma16(kf0, qf[1][0], st[g][1]);
            st[g][1] = mfma16(kf1, qf[1][1], st[g][1]);
        }

        if (anyz) {
#pragma unroll
            for (int g = 0; g < 4; ++g) {
                int4 mv = *(const int4*)(mrow + kv0 + g * 16 + hi * 4);
#pragma unroll
                for (int qh = 0; qh < 2; ++qh) {
                    st[g][qh][0] = mv.x ? st[g][qh][0] : -INFINITY;
                    st[g][qh][1] = mv.y ? st[g][qh][1] : -INFINITY;
                    st[g][qh][2] = mv.z ? st[g][qh][2] : -INFINITY;
                    st[g][qh][3] = mv.w ? st[g][qh][3] : -INFINITY;
                }
            }
        }

        // ---- p = exp2(s), straight to bf16 ----
        bf16x8 pB[2][2];                 // [qh][ks]
#pragma unroll
        for (int qh = 0; qh < 2; ++qh)
#pragma unroll
            for (int g = 0; g < 4; ++g)
#pragma unroll
                for (int r = 0; r < 4; ++r)
                    pB[qh][g >> 1][(g & 1) * 4 + r] =
                        (__bf16)__builtin_exp2f(st[g][qh][r]);

        // ---- PV + denominator (mfma with ones-row), T5 priority hint ----
        __builtin_amdgcn_s_setprio(1);
        accL[0] = mfma16(onesf, pB[0][0], accL[0]);
        accL[0] = mfma16(onesf, pB[0][1], accL[0]);
        accL[1] = mfma16(onesf, pB[1][0], accL[1]);
        accL[1] = mfma16(onesf, pB[1][1], accL[1]);
#pragma unroll
        for (int dt = 0; dt < 4; ++dt) {
            const char* vrow = Vc + (dt * 16 + lr) * 128;
#pragma unroll
            for (int ks = 0; ks < 2; ++ks) {
                bf16x8 vf = *(const bf16x8*)(vrow + ((ks * 64 + hi * 16) ^ sw));
                acc[dt][0] = mfma16(vf, pB[0][ks], acc[dt][0]);
                acc[dt][1] = mfma16(vf, pB[1][ks], acc[dt][1]);
            }
        }
        __builtin_amdgcn_s_setprio(0);
    };

    STAGE(0, 0);
    const int NT = S_ / 64;              // 32, even
    for (int ti = 0; ti < NT; ti += 2) {
        __syncthreads();
        if (ti + 1 < NT) STAGE(1, (ti + 1) * 64);
        TILE(0, ti * 64);
        __syncthreads();
        if (ti + 2 < NT) STAGE(0, (ti + 2) * 64);
        TILE(1, (ti + 1) * 64);
    }

    float inv[2] = {1.0f / accL[0][0], 1.0f / accL[1][0]};
#pragma unroll
    for (int qh = 0; qh < 2; ++qh) {
        size_t obase = ((size_t)(b * S_ + qbase + qh * 16 + lr)) * H_ + head * HD_;
#pragma unroll
        for (int dt = 0; dt < 4; ++dt) {
            bf16x4 o;
#pragma unroll
            for (int r = 0; r < 4; ++r) o[r] = (__bf16)(acc[dt][qh][r] * inv[qh]);
            *(bf16x4*)(aout + obase + dt * 16 + hi * 4) = o;
        }
    }
}

extern "C" void kernel_launch(void* const* d_in, const int* in_sizes, int n_in,
                              void* d_out, int out_size, void* d_ws, size_t ws_size,
                              hipStream_t stream) {
    const float* x  = (const float*)d_in[0];
    const int* mask = (const int*)d_in[1];
    const float* Wq = (const float*)d_in[2];
    const float* Wk = (const float*)d_in[3];
    const float* Wv = (const float*)d_in[4];
    const float* Wo = (const float*)d_in[5];
    float* out = (float*)d_out;

    char* ws = (char*)d_ws;
    bf16* xb    = (bf16*)ws;                               // 16 MB (reused as attn out)
    bf16* wqkv  = (bf16*)(ws + (size_t)16 * 1048576);      // 6 MB
    bf16* wob   = (bf16*)(ws + (size_t)22 * 1048576);      // 2 MB
    bf16* qr    = (bf16*)(ws + (size_t)24 * 1048576);      // 16 MB
    bf16* kr    = (bf16*)(ws + (size_t)40 * 1048576);      // 16 MB
    bf16* vtw   = (bf16*)(ws + (size_t)56 * 1048576);      // 16 MB (V^T: [bh][d][perm(s)])
    float* cosT = (float*)(ws + (size_t)72 * 1048576);     // 256 KB
    float* sinT = (float*)(ws + (size_t)72 * 1048576 + 262144);

    // fused prep: x->bf16, weights->bf16, RoPE tables (one launch)
    k_prep<<<12544, 256, 0, stream>>>(x, Wq, Wk, Wv, Wo, xb, wqkv, wob, cosT, sinT);

    // QKV projection + RoPE + relayout (V transposed+permuted, Q exp2-scaled)
    k_gemm<0><<<dim3(24, 64), 256, 0, stream>>>(xb, wqkv, qr, kr, vtw, cosT, sinT, nullptr);

    // flash attention -> (B,S,H) bf16 (reuse xb region)
    k_attn<<<dim3(8, 64), 512, 0, stream>>>(qr, kr, vtw, mask, xb);

    // output projection -> fp32
    k_gemm<1><<<dim3(8, 64), 256, 0, stream>>>(xb, wob, nullptr, nullptr, nullptr,
                                               cosT, sinT, out);
}